// Round 1
// baseline (10299.982 us; speedup 1.0000x reference)
//
#include <hip/hip_runtime.h>

// ---------------------------------------------------------------------------
// GraphMatchNet: 3x { decomposed message GEMM, dual flash attention, GRU }
// All f32 this round (correctness baseline). D=256 hardcoded.
// ---------------------------------------------------------------------------

__global__ void k_gather(const float* __restrict__ emb, const int* __restrict__ x,
                         float* __restrict__ h) {
  int v = blockIdx.x, d = threadIdx.x;
  h[v * 256 + d] = emb[(size_t)x[v] * 256 + d];
}

// P[a][o] = sum_k edge_embed[a][k] * Wm[o][512+k]   (16 x 256)
__global__ void k_edgeproj(const float* __restrict__ ee, const float* __restrict__ Wm,
                           float* __restrict__ P) {
  __shared__ float row[256];
  int a = blockIdx.x, o = threadIdx.x;
  row[o] = ee[a * 256 + o];
  __syncthreads();
  float s = 0.f;
#pragma unroll 8
  for (int k = 0; k < 256; k++) s += row[k] * Wm[o * 768 + 512 + k];
  P[a * 256 + o] = s;
}

__global__ void k_count(const int* __restrict__ ei, const int* __restrict__ ea,
                        unsigned* __restrict__ cnt, unsigned* __restrict__ deg, int E) {
  int e = blockIdx.x * 256 + threadIdx.x;
  if (e >= E) return;
  int dst = ei[E + e];
  atomicAdd(&cnt[dst * 16 + ea[e]], 1u);
  atomicAdd(&deg[dst], 1u);
}

__global__ void k_scan(const unsigned* __restrict__ deg, unsigned* __restrict__ off,
                       unsigned* __restrict__ cur, int N) {
  __shared__ unsigned part[256];
  int tid = threadIdx.x;
  int per = N >> 8;
  unsigned s = 0;
  for (int i = 0; i < per; i++) s += deg[tid * per + i];
  part[tid] = s;
  __syncthreads();
  if (tid == 0) {
    unsigned run = 0;
    for (int i = 0; i < 256; i++) { unsigned t = part[i]; part[i] = run; run += t; }
  }
  __syncthreads();
  unsigned run = part[tid];
  for (int i = 0; i < per; i++) {
    unsigned dv = deg[tid * per + i];
    off[tid * per + i] = run;
    cur[tid * per + i] = run;
    run += dv;
  }
  if (tid == 255) off[N] = run;
}

__global__ void k_fill(const int* __restrict__ ei, unsigned* __restrict__ cur,
                       int* __restrict__ csr, int E) {
  int e = blockIdx.x * 256 + threadIdx.x;
  if (e >= E) return;
  int dst = ei[E + e];
  unsigned pos = atomicAdd(&cur[dst], 1u);
  csr[pos] = ei[e];  // src
}

// C[v][o] = deg[v]*bm[o] + sum_a cnt[v][a]*P[a][o]   (layer-invariant)
__global__ void k_cconst(const unsigned* __restrict__ cnt, const unsigned* __restrict__ deg,
                         const float* __restrict__ P, const float* __restrict__ bm,
                         float* __restrict__ C) {
  int v = blockIdx.x, o = threadIdx.x;
  float s = (float)deg[v] * bm[o];
#pragma unroll
  for (int a = 0; a < 16; a++) s += (float)cnt[v * 16 + a] * P[a * 256 + o];
  C[v * 256 + o] = s;
}

// agg[v] = sum over in-neighbors of h[src]
__global__ void k_aggh(const float* __restrict__ h, const int* __restrict__ csr,
                       const unsigned* __restrict__ off, float* __restrict__ agg) {
  int v = blockIdx.x, d = threadIdx.x;
  unsigned i0 = off[v], i1 = off[v + 1];
  float s = 0.f;
  for (unsigned i = i0; i < i1; i++) s += h[csr[i] * 256 + d];
  agg[v * 256 + d] = s;
}

// Generic 64x64-tile f32 GEMM, out[row][col] = sum_k A(row,k)*W[col][k] (+epilogue)
// MODE 0 (M):  A=[deg.*h | agg]       K=512, W=Wm (stride 768), +Cmat
// MODE 1 (GI): A=[M | h-att]          K=512, W=W_ih (stride 512), +bias
// MODE 2 (GH): A=h                    K=256, W=W_hh (stride 256), +bias
template <int MODE>
__global__ __launch_bounds__(256) void k_gemm(
    const float* __restrict__ A0, const float* __restrict__ A1, const float* __restrict__ A2,
    const unsigned* __restrict__ deg, const float* __restrict__ W,
    const float* __restrict__ bias, const float* __restrict__ Cmat,
    float* __restrict__ out, int Ostride, int wstride, int K) {
  __shared__ float As[32][68];  // [k][row], pad 68 keeps float4 16B-aligned
  __shared__ float Bs[32][68];  // [k][col]
  int tid = threadIdx.x;
  int ty = tid >> 4, tx = tid & 15;
  int row0 = blockIdx.x * 64, col0 = blockIdx.y * 64;
  int lc = tid & 31, lr = tid >> 5;
  float acc[4][4] = {};
  for (int kt = 0; kt < K; kt += 32) {
    __syncthreads();
#pragma unroll
    for (int n = 0; n < 8; n++) {
      int r = lr + n * 8;
      int row = row0 + r;
      int k = kt + lc;
      float av;
      if (MODE == 0)
        av = (k < 256) ? A0[row * 256 + k] * (float)deg[row] : A1[row * 256 + k - 256];
      else if (MODE == 1)
        av = (k < 256) ? A0[row * 256 + k]
                       : (A1[row * 256 + k - 256] - A2[row * 256 + k - 256]);
      else
        av = A0[row * 256 + k];
      As[lc][r] = av;
      Bs[lc][r] = W[(col0 + r) * wstride + k];
    }
    __syncthreads();
#pragma unroll
    for (int k = 0; k < 32; k++) {
      float4 a4 = *(const float4*)&As[k][ty * 4];
      float4 b4 = *(const float4*)&Bs[k][tx * 4];
      float av[4] = {a4.x, a4.y, a4.z, a4.w};
      float bv[4] = {b4.x, b4.y, b4.z, b4.w};
#pragma unroll
      for (int a = 0; a < 4; a++)
#pragma unroll
        for (int b = 0; b < 4; b++) acc[a][b] += av[a] * bv[b];
    }
  }
#pragma unroll
  for (int a = 0; a < 4; a++) {
    int row = row0 + ty * 4 + a;
    int col = col0 + tx * 4;
    float4 r4;
    if (MODE == 0) {
      float4 c4 = *(const float4*)&Cmat[row * 256 + col];
      r4 = make_float4(acc[a][0] + c4.x, acc[a][1] + c4.y, acc[a][2] + c4.z, acc[a][3] + c4.w);
    } else {
      float4 b4 = *(const float4*)&bias[col];
      r4 = make_float4(acc[a][0] + b4.x, acc[a][1] + b4.y, acc[a][2] + b4.z, acc[a][3] + b4.w);
    }
    *(float4*)&out[row * Ostride + col] = r4;
  }
}

// Flash attention, no scale: Out = softmax_rows(Q @ KV^T) @ KV.
// blockIdx.y picks direction (0: Q=h1,KV=h2,Out=att1; 1: swapped).
// 512 threads, BR=64 query rows per block, BC=64 keys per tile, D=256.
__global__ __launch_bounds__(512) void k_flash(
    const float* __restrict__ h1, const float* __restrict__ h2,
    float* __restrict__ att1, float* __restrict__ att2, int N) {
  const float* Q;
  const float* KV;
  float* Out;
  if (blockIdx.y == 0) { Q = h1; KV = h2; Out = att1; }
  else                 { Q = h2; KV = h1; Out = att2; }
  __shared__ float Qs[32][68];  // [k][row]
  __shared__ float Ks[32][68];  // [k][key]
  __shared__ float PL[64][68];  // [key][row]
  __shared__ float Vs[64][68];  // [key][col-chunk]
  int tid = threadIdx.x;
  int ty = tid >> 4, tx = tid & 15;  // ty 0..31 (2 rows each), tx 0..15 (4 keys/cols each)
  int row0 = blockIdx.x * 64;
  int lc = tid & 31, lr = tid >> 5;
  float O[2][16];
  float m_r[2] = {-1e30f, -1e30f};
  float l_r[2] = {0.f, 0.f};
#pragma unroll
  for (int a = 0; a < 2; a++)
#pragma unroll
    for (int j = 0; j < 16; j++) O[a][j] = 0.f;

  for (int kt = 0; kt < N; kt += 64) {
    float S[2][4] = {};
    for (int dk = 0; dk < 256; dk += 32) {
      __syncthreads();
#pragma unroll
      for (int n = 0; n < 4; n++) {
        int r = lr + n * 16;
        Qs[lc][r] = Q[(row0 + r) * 256 + dk + lc];
        Ks[lc][r] = KV[(kt + r) * 256 + dk + lc];
      }
      __syncthreads();
#pragma unroll
      for (int k = 0; k < 32; k++) {
        float2 a2 = *(const float2*)&Qs[k][ty * 2];
        float4 b4 = *(const float4*)&Ks[k][tx * 4];
        float av[2] = {a2.x, a2.y};
        float bv[4] = {b4.x, b4.y, b4.z, b4.w};
#pragma unroll
        for (int a = 0; a < 2; a++)
#pragma unroll
          for (int b = 0; b < 4; b++) S[a][b] += av[a] * bv[b];
      }
    }
    // online softmax along keys; row stats reduced across tx (lane bits 0..3)
#pragma unroll
    for (int a = 0; a < 2; a++) {
      float rmax = fmaxf(fmaxf(S[a][0], S[a][1]), fmaxf(S[a][2], S[a][3]));
#pragma unroll
      for (int sh = 1; sh < 16; sh <<= 1) rmax = fmaxf(rmax, __shfl_xor(rmax, sh));
      float mn = fmaxf(m_r[a], rmax);
      float al = __expf(m_r[a] - mn);
      m_r[a] = mn;
      float rs = 0.f;
#pragma unroll
      for (int b = 0; b < 4; b++) { S[a][b] = __expf(S[a][b] - mn); rs += S[a][b]; }
#pragma unroll
      for (int sh = 1; sh < 16; sh <<= 1) rs += __shfl_xor(rs, sh);
      l_r[a] = l_r[a] * al + rs;
#pragma unroll
      for (int j = 0; j < 16; j++) O[a][j] *= al;
    }
    // store P transposed: PL[key][row]  (safe: dk-loop syncs separate prior reads)
#pragma unroll
    for (int b = 0; b < 4; b++) {
      float2 p2 = make_float2(S[0][b], S[1][b]);
      *(float2*)&PL[tx * 4 + b][ty * 2] = p2;
    }
#pragma unroll
    for (int cc = 0; cc < 4; cc++) {
      __syncthreads();  // PL visible; previous Vs reads done
#pragma unroll
      for (int n = 0; n < 8; n++) {
        int idx = tid + n * 512;
        int r = idx >> 6, c = idx & 63;
        Vs[r][c] = KV[(kt + r) * 256 + cc * 64 + c];
      }
      __syncthreads();
#pragma unroll 4
      for (int j = 0; j < 64; j++) {
        float2 p2 = *(const float2*)&PL[j][ty * 2];
        float4 v4 = *(const float4*)&Vs[j][tx * 4];
        float pv[2] = {p2.x, p2.y};
        float vv[4] = {v4.x, v4.y, v4.z, v4.w};
#pragma unroll
        for (int a = 0; a < 2; a++)
#pragma unroll
          for (int u = 0; u < 4; u++) O[a][cc * 4 + u] += pv[a] * vv[u];
      }
    }
  }
#pragma unroll
  for (int a = 0; a < 2; a++) {
    float inv = 1.f / l_r[a];
    int row = row0 + ty * 2 + a;
#pragma unroll
    for (int cc = 0; cc < 4; cc++) {
      float4 o4 = make_float4(O[a][cc * 4 + 0] * inv, O[a][cc * 4 + 1] * inv,
                              O[a][cc * 4 + 2] * inv, O[a][cc * 4 + 3] * inv);
      *(float4*)&Out[row * 256 + cc * 64 + tx * 4] = o4;
    }
  }
}

__global__ void k_gru(float* __restrict__ h, const float* __restrict__ gi,
                      const float* __restrict__ gh) {
  int i = blockIdx.x * 256 + threadIdx.x;
  int v = i >> 8, d = i & 255;
  float gir = gi[v * 768 + d], giz = gi[v * 768 + 256 + d], gin = gi[v * 768 + 512 + d];
  float ghr = gh[v * 768 + d], ghz = gh[v * 768 + 256 + d], ghn = gh[v * 768 + 512 + d];
  float r = 1.f / (1.f + __expf(-(gir + ghr)));
  float z = 1.f / (1.f + __expf(-(giz + ghz)));
  float n = tanhf(gin + r * ghn);
  h[i] = (1.f - z) * n + z * h[i];
}

__global__ void k_gate(const float* __restrict__ h, const float* __restrict__ Wg,
                       const float* __restrict__ bg, float* __restrict__ g) {
  int wave = threadIdx.x >> 6, lane = threadIdx.x & 63;
  int v = blockIdx.x * 4 + wave;
  float s = 0.f;
#pragma unroll
  for (int k = lane; k < 256; k += 64) s += h[v * 256 + k] * Wg[k];
#pragma unroll
  for (int sh = 32; sh > 0; sh >>= 1) s += __shfl_xor(s, sh);
  if (lane == 0) g[v] = 1.f / (1.f + __expf(-(s + bg[0])));
}

__global__ void k_poolstats(const float* __restrict__ g, float* __restrict__ stats, int N) {
  __shared__ float red[256];
  int tid = threadIdx.x;
  float mx = -1e30f;
  for (int i = tid; i < N; i += 256) mx = fmaxf(mx, g[i]);
  red[tid] = mx;
  __syncthreads();
  for (int s = 128; s > 0; s >>= 1) {
    if (tid < s) red[tid] = fmaxf(red[tid], red[tid + s]);
    __syncthreads();
  }
  float M = red[0];
  __syncthreads();
  float sm = 0.f;
  for (int i = tid; i < N; i += 256) sm += __expf(g[i] - M);
  red[tid] = sm;
  __syncthreads();
  for (int s = 128; s > 0; s >>= 1) {
    if (tid < s) red[tid] += red[tid + s];
    __syncthreads();
  }
  if (tid == 0) { stats[0] = M; stats[1] = red[0]; }
}

__global__ void k_poolpart(const float* __restrict__ g, const float* __restrict__ h,
                           const float* __restrict__ stats, float* __restrict__ part, int N) {
  int c = blockIdx.x, o = threadIdx.x;
  int per = N / 32;
  float M = stats[0];
  float s = 0.f;
  for (int v = c * per; v < (c + 1) * per; v++) s += __expf(g[v] - M) * h[v * 256 + o];
  part[c * 256 + o] = s;
}

__global__ void k_poolfin(const float* __restrict__ part, const float* __restrict__ stats,
                          float* __restrict__ out) {
  int o = threadIdx.x;
  float s = 0.f;
#pragma unroll
  for (int c = 0; c < 32; c++) s += part[c * 256 + o];
  out[o] = s / stats[1];
}

extern "C" void kernel_launch(void* const* d_in, const int* in_sizes, int n_in,
                              void* d_out, int out_size, void* d_ws, size_t ws_size,
                              hipStream_t stream) {
  const int* x1 = (const int*)d_in[0];
  const int* x2 = (const int*)d_in[1];
  const int* ei1 = (const int*)d_in[2];
  const int* ei2 = (const int*)d_in[3];
  const int* ea1 = (const int*)d_in[4];
  const int* ea2 = (const int*)d_in[5];
  const float* embed = (const float*)d_in[6];
  const float* eemb = (const float*)d_in[7];
  const float* Wm = (const float*)d_in[8];
  const float* bm = (const float*)d_in[9];
  const float* Wih = (const float*)d_in[10];
  const float* Whh = (const float*)d_in[11];
  const float* bih = (const float*)d_in[12];
  const float* bhh = (const float*)d_in[13];
  const float* Wg = (const float*)d_in[14];
  const float* bg = (const float*)d_in[15];
  const int N = in_sizes[0];   // 8192
  const int E = in_sizes[4];   // 131072
  float* out = (float*)d_out;

  char* ws = (char*)d_ws;
  size_t ofs = 0;
  auto alloc = [&](size_t bytes) -> void* {
    void* p = ws + ofs;
    ofs = (ofs + bytes + 255) & ~(size_t)255;
    return p;
  };
  size_t ND4 = (size_t)N * 256 * 4;
  float* h1 = (float*)alloc(ND4);
  float* h2 = (float*)alloc(ND4);
  float* agg = (float*)alloc(ND4);
  float* M1 = (float*)alloc(ND4);
  float* M2 = (float*)alloc(ND4);
  float* at1 = (float*)alloc(ND4);
  float* at2 = (float*)alloc(ND4);
  float* C1 = (float*)alloc(ND4);
  float* C2 = (float*)alloc(ND4);
  float* gi = (float*)alloc((size_t)N * 768 * 4);
  float* gh = (float*)alloc((size_t)N * 768 * 4);
  float* P = (float*)alloc(16 * 256 * 4);
  unsigned* cnt1 = (unsigned*)alloc((size_t)N * 16 * 4);
  unsigned* cnt2 = (unsigned*)alloc((size_t)N * 16 * 4);
  unsigned* deg1 = (unsigned*)alloc((size_t)N * 4);
  unsigned* deg2 = (unsigned*)alloc((size_t)N * 4);
  unsigned* off1 = (unsigned*)alloc((size_t)(N + 1) * 4);
  unsigned* off2 = (unsigned*)alloc((size_t)(N + 1) * 4);
  unsigned* cur1 = (unsigned*)alloc((size_t)N * 4);
  unsigned* cur2 = (unsigned*)alloc((size_t)N * 4);
  int* csr1 = (int*)alloc((size_t)E * 4);
  int* csr2 = (int*)alloc((size_t)E * 4);
  float* gbuf = (float*)alloc((size_t)N * 4);
  float* partb = (float*)alloc(32 * 256 * 4);
  float* stats = (float*)alloc(256);

  // zero the contiguous cnt1|cnt2|deg1|deg2 region (re-zero every launch)
  size_t zbytes = (size_t)((char*)(deg2 + N) - (char*)cnt1);
  hipMemsetAsync(cnt1, 0, zbytes, stream);

  k_gather<<<N, 256, 0, stream>>>(embed, x1, h1);
  k_gather<<<N, 256, 0, stream>>>(embed, x2, h2);
  k_edgeproj<<<16, 256, 0, stream>>>(eemb, Wm, P);
  int eb = (E + 255) / 256;
  k_count<<<eb, 256, 0, stream>>>(ei1, ea1, cnt1, deg1, E);
  k_count<<<eb, 256, 0, stream>>>(ei2, ea2, cnt2, deg2, E);
  k_scan<<<1, 256, 0, stream>>>(deg1, off1, cur1, N);
  k_scan<<<1, 256, 0, stream>>>(deg2, off2, cur2, N);
  k_fill<<<eb, 256, 0, stream>>>(ei1, cur1, csr1, E);
  k_fill<<<eb, 256, 0, stream>>>(ei2, cur2, csr2, E);
  k_cconst<<<N, 256, 0, stream>>>(cnt1, deg1, P, bm, C1);
  k_cconst<<<N, 256, 0, stream>>>(cnt2, deg2, P, bm, C2);

  dim3 gM(N / 64, 4), gG(N / 64, 12);
  for (int layer = 0; layer < 3; layer++) {
    k_aggh<<<N, 256, 0, stream>>>(h1, csr1, off1, agg);
    k_gemm<0><<<gM, 256, 0, stream>>>(h1, agg, nullptr, deg1, Wm, nullptr, C1, M1, 256, 768, 512);
    k_aggh<<<N, 256, 0, stream>>>(h2, csr2, off2, agg);
    k_gemm<0><<<gM, 256, 0, stream>>>(h2, agg, nullptr, deg2, Wm, nullptr, C2, M2, 256, 768, 512);
    k_flash<<<dim3(N / 64, 2), 512, 0, stream>>>(h1, h2, at1, at2, N);
    // graph 1 GRU (updates h1 in place; all consumers of old h1 already ran)
    k_gemm<2><<<gG, 256, 0, stream>>>(h1, nullptr, nullptr, nullptr, Whh, bhh, nullptr, gh, 768, 256, 256);
    k_gemm<1><<<gG, 256, 0, stream>>>(M1, h1, at1, nullptr, Wih, bih, nullptr, gi, 768, 512, 512);
    k_gru<<<N, 256, 0, stream>>>(h1, gi, gh);
    // graph 2 GRU
    k_gemm<2><<<gG, 256, 0, stream>>>(h2, nullptr, nullptr, nullptr, Whh, bhh, nullptr, gh, 768, 256, 256);
    k_gemm<1><<<gG, 256, 0, stream>>>(M2, h2, at2, nullptr, Wih, bih, nullptr, gi, 768, 512, 512);
    k_gru<<<N, 256, 0, stream>>>(h2, gi, gh);
  }

  k_gate<<<N / 4, 256, 0, stream>>>(h1, Wg, bg, gbuf);
  k_poolstats<<<1, 256, 0, stream>>>(gbuf, stats, N);
  k_poolpart<<<32, 256, 0, stream>>>(gbuf, h1, stats, partb, N);
  k_poolfin<<<1, 256, 0, stream>>>(partb, stats, out);
  k_gate<<<N / 4, 256, 0, stream>>>(h2, Wg, bg, gbuf);
  k_poolstats<<<1, 256, 0, stream>>>(gbuf, stats, N);
  k_poolpart<<<32, 256, 0, stream>>>(gbuf, h2, stats, partb, N);
  k_poolfin<<<1, 256, 0, stream>>>(partb, stats, out + 256);
}

// Round 2
// 2848.133 us; speedup vs baseline: 3.6164x; 3.6164x over previous
//
#include <hip/hip_runtime.h>

typedef __bf16 bf16;
typedef __attribute__((ext_vector_type(8))) __bf16 bf16x8;
typedef __attribute__((ext_vector_type(4))) float f32x4;

// ---------------------------------------------------------------------------
// GraphMatchNet: 3x { decomposed message GEMM, dual MFMA flash attn, GRU }
// ---------------------------------------------------------------------------

__global__ void k_gather(const float* __restrict__ emb, const int* __restrict__ x,
                         float* __restrict__ h) {
  int v = blockIdx.x, d = threadIdx.x;
  h[v * 256 + d] = emb[(size_t)x[v] * 256 + d];
}

__global__ void k_edgeproj(const float* __restrict__ ee, const float* __restrict__ Wm,
                           float* __restrict__ P) {
  __shared__ float row[256];
  int a = blockIdx.x, o = threadIdx.x;
  row[o] = ee[a * 256 + o];
  __syncthreads();
  float s = 0.f;
#pragma unroll 8
  for (int k = 0; k < 256; k++) s += row[k] * Wm[o * 768 + 512 + k];
  P[a * 256 + o] = s;
}

__global__ void k_count(const int* __restrict__ ei, const int* __restrict__ ea,
                        unsigned* __restrict__ cnt, unsigned* __restrict__ deg, int E) {
  int e = blockIdx.x * 256 + threadIdx.x;
  if (e >= E) return;
  int dst = ei[E + e];
  atomicAdd(&cnt[dst * 16 + ea[e]], 1u);
  atomicAdd(&deg[dst], 1u);
}

__global__ void k_scan(const unsigned* __restrict__ deg, unsigned* __restrict__ off,
                       unsigned* __restrict__ cur, int N) {
  __shared__ unsigned part[256];
  int tid = threadIdx.x;
  int per = N >> 8;
  unsigned s = 0;
  for (int i = 0; i < per; i++) s += deg[tid * per + i];
  part[tid] = s;
  __syncthreads();
  if (tid == 0) {
    unsigned run = 0;
    for (int i = 0; i < 256; i++) { unsigned t = part[i]; part[i] = run; run += t; }
  }
  __syncthreads();
  unsigned run = part[tid];
  for (int i = 0; i < per; i++) {
    unsigned dv = deg[tid * per + i];
    off[tid * per + i] = run;
    cur[tid * per + i] = run;
    run += dv;
  }
  if (tid == 255) off[N] = run;
}

__global__ void k_fill(const int* __restrict__ ei, unsigned* __restrict__ cur,
                       int* __restrict__ csr, int E) {
  int e = blockIdx.x * 256 + threadIdx.x;
  if (e >= E) return;
  int dst = ei[E + e];
  unsigned pos = atomicAdd(&cur[dst], 1u);
  csr[pos] = ei[e];  // src
}

__global__ void k_cconst(const unsigned* __restrict__ cnt, const unsigned* __restrict__ deg,
                         const float* __restrict__ P, const float* __restrict__ bm,
                         float* __restrict__ C) {
  int v = blockIdx.x, o = threadIdx.x;
  float s = (float)deg[v] * bm[o];
#pragma unroll
  for (int a = 0; a < 16; a++) s += (float)cnt[v * 16 + a] * P[a * 256 + o];
  C[v * 256 + o] = s;
}

__global__ void k_aggh(const float* __restrict__ h, const int* __restrict__ csr,
                       const unsigned* __restrict__ off, float* __restrict__ agg) {
  int v = blockIdx.x, d = threadIdx.x;
  unsigned i0 = off[v], i1 = off[v + 1];
  float s = 0.f;
  for (unsigned i = i0; i < i1; i++) s += h[csr[i] * 256 + d];
  agg[v * 256 + d] = s;
}

// Generic 64x64-tile f32 GEMM (see R1); MODE 0: M, 1: GI, 2: GH
template <int MODE>
__global__ __launch_bounds__(256) void k_gemm(
    const float* __restrict__ A0, const float* __restrict__ A1, const float* __restrict__ A2,
    const unsigned* __restrict__ deg, const float* __restrict__ W,
    const float* __restrict__ bias, const float* __restrict__ Cmat,
    float* __restrict__ out, int Ostride, int wstride, int K) {
  __shared__ float As[32][68];
  __shared__ float Bs[32][68];
  int tid = threadIdx.x;
  int ty = tid >> 4, tx = tid & 15;
  int row0 = blockIdx.x * 64, col0 = blockIdx.y * 64;
  int lc = tid & 31, lr = tid >> 5;
  float acc[4][4] = {};
  for (int kt = 0; kt < K; kt += 32) {
    __syncthreads();
#pragma unroll
    for (int n = 0; n < 8; n++) {
      int r = lr + n * 8;
      int row = row0 + r;
      int k = kt + lc;
      float av;
      if (MODE == 0)
        av = (k < 256) ? A0[row * 256 + k] * (float)deg[row] : A1[row * 256 + k - 256];
      else if (MODE == 1)
        av = (k < 256) ? A0[row * 256 + k]
                       : (A1[row * 256 + k - 256] - A2[row * 256 + k - 256]);
      else
        av = A0[row * 256 + k];
      As[lc][r] = av;
      Bs[lc][r] = W[(col0 + r) * wstride + k];
    }
    __syncthreads();
#pragma unroll
    for (int k = 0; k < 32; k++) {
      float4 a4 = *(const float4*)&As[k][ty * 4];
      float4 b4 = *(const float4*)&Bs[k][tx * 4];
      float av[4] = {a4.x, a4.y, a4.z, a4.w};
      float bv[4] = {b4.x, b4.y, b4.z, b4.w};
#pragma unroll
      for (int a = 0; a < 4; a++)
#pragma unroll
        for (int b = 0; b < 4; b++) acc[a][b] += av[a] * bv[b];
    }
  }
#pragma unroll
  for (int a = 0; a < 4; a++) {
    int row = row0 + ty * 4 + a;
    int col = col0 + tx * 4;
    float4 r4;
    if (MODE == 0) {
      float4 c4 = *(const float4*)&Cmat[row * 256 + col];
      r4 = make_float4(acc[a][0] + c4.x, acc[a][1] + c4.y, acc[a][2] + c4.z, acc[a][3] + c4.w);
    } else {
      float4 b4 = *(const float4*)&bias[col];
      r4 = make_float4(acc[a][0] + b4.x, acc[a][1] + b4.y, acc[a][2] + b4.z, acc[a][3] + b4.w);
    }
    *(float4*)&out[row * Ostride + col] = r4;
  }
}

// convert h (f32 [N][256]) -> hb (bf16 [N][256]) and hbt (bf16 [256][N])
__global__ void k_cvt(const float* __restrict__ h, bf16* __restrict__ hb,
                      bf16* __restrict__ hbt, int N) {
  __shared__ bf16 t[64][68];
  int v0 = blockIdx.x * 64, d0 = blockIdx.y * 64;
  int tid = threadIdx.x;
#pragma unroll
  for (int i = 0; i < 4; i++) {
    int e = tid + i * 1024;
    int r = e >> 6, c = e & 63;
    bf16 b = (bf16)h[(size_t)(v0 + r) * 256 + d0 + c];
    hb[(size_t)(v0 + r) * 256 + d0 + c] = b;
    t[r][c] = b;
  }
  __syncthreads();
#pragma unroll
  for (int i = 0; i < 4; i++) {
    int e = tid + i * 1024;
    int dr = e >> 6, vc = e & 63;
    hbt[(size_t)(d0 + dr) * N + v0 + vc] = t[vc][dr];
  }
}

// ---------------------------------------------------------------------------
// MFMA flash attention. Out = softmax_rows(Q @ KV^T) @ KV, f32 out.
// Swapped QK^T: S^T = mfma(A=K_frag, B=Q_frag) -> lane holds col q=lane&15,
// rows key = nt*16 + 4g + reg (g = lane>>4). PV: O^T = mfma(A=Vt, B=P) where
// Vt is staged key-PERMUTED ([d][g*16+nt*4+reg]) so the B(P) fragment is
// exactly the S^T accumulator layout (zero cross-lane movement).
// LDS XOR-swizzle (slot ^ row&7) on both tiles kills stride conflicts.
// ---------------------------------------------------------------------------
__global__ __launch_bounds__(256, 1) void k_flash_mfma(
    const bf16* __restrict__ hb1, const bf16* __restrict__ hbt1,
    const bf16* __restrict__ hb2, const bf16* __restrict__ hbt2,
    float* __restrict__ att1, float* __restrict__ att2, int N) {
  const bf16 *Q, *K, *Kt;
  float* Out;
  if (blockIdx.y == 0) { Q = hb1; K = hb2; Kt = hbt2; Out = att1; }
  else                 { Q = hb2; K = hb1; Kt = hbt1; Out = att2; }
  __shared__ bf16 Klds[64 * 256];   // [key][d/8-slot swizzled]   32 KB
  __shared__ bf16 Vlds[256 * 64];   // [d][key-perm swizzled]     32 KB
  int tid = threadIdx.x;
  int w = tid >> 6, l = tid & 63;
  int lane15 = l & 15, g = l >> 4;
  int row0 = blockIdx.x * 64 + w * 16;

  // Q fragments (B operand): q = row0+lane15, k = kk*32 + g*8 + i
  bf16x8 qf[8];
  {
    const bf16* qp = Q + (size_t)(row0 + lane15) * 256 + g * 8;
#pragma unroll
    for (int kk = 0; kk < 8; kk++) qf[kk] = *(const bf16x8*)(qp + kk * 32);
  }
  f32x4 Oacc[16];
#pragma unroll
  for (int i = 0; i < 16; i++) Oacc[i] = (f32x4){0.f, 0.f, 0.f, 0.f};
  float m_run = -1e30f, l_run = 0.f;

  for (int kt = 0; kt < N; kt += 64) {
    __syncthreads();
    // stage K tile: 2048 16B chunks, swizzled slot ^= key&7
#pragma unroll
    for (int i = 0; i < 8; i++) {
      int c = tid + i * 256;
      int key = c >> 5, sl = c & 31;
      float4 v = *(const float4*)(const void*)(K + (size_t)(kt + key) * 256 + sl * 8);
      *(float4*)(void*)(Klds + key * 256 + ((sl ^ (key & 7)) * 8)) = v;
    }
    // stage Vt tile: key-permuted (pos = g*16+nt*4+reg <- key = nt*16+4g+reg),
    // 8B granules, swizzled 16B-slot ^= d&7
#pragma unroll
    for (int i = 0; i < 16; i++) {
      int c = tid + i * 256;
      int d = c >> 4, j = c & 15;
      float2 v = *(const float2*)(const void*)(Kt + (size_t)d * N + kt + (j & 3) * 16 + (j >> 2) * 4);
      int slot = (j >> 1) ^ (d & 7);
      *(float2*)(void*)(Vlds + d * 64 + slot * 8 + (j & 1) * 4) = v;
    }
    __syncthreads();

    // QK^T (swapped): Sacc[nt][reg] = S[row0+q][key=nt*16+4g+reg], q=lane15
    f32x4 Sacc[4];
#pragma unroll
    for (int i = 0; i < 4; i++) Sacc[i] = (f32x4){0.f, 0.f, 0.f, 0.f};
#pragma unroll
    for (int kk = 0; kk < 8; kk++) {
#pragma unroll
      for (int nt = 0; nt < 4; nt++) {
        int key = nt * 16 + lane15;
        int slot = (kk * 4 + g) ^ (key & 7);
        bf16x8 kf = *(const bf16x8*)(Klds + key * 256 + slot * 8);
        Sacc[nt] = __builtin_amdgcn_mfma_f32_16x16x32_bf16(kf, qf[kk], Sacc[nt], 0, 0, 0);
      }
    }
    // online softmax over keys (lane-local + xor over lane bits 4,5)
    float tmax = -1e30f;
#pragma unroll
    for (int nt = 0; nt < 4; nt++)
#pragma unroll
      for (int r = 0; r < 4; r++) tmax = fmaxf(tmax, Sacc[nt][r]);
    tmax = fmaxf(tmax, __shfl_xor(tmax, 16));
    tmax = fmaxf(tmax, __shfl_xor(tmax, 32));
    float m_new = fmaxf(m_run, tmax);
    float alpha = __expf(m_run - m_new);
    float ts = 0.f;
#pragma unroll
    for (int nt = 0; nt < 4; nt++)
#pragma unroll
      for (int r = 0; r < 4; r++) {
        float p = __expf(Sacc[nt][r] - m_new);
        Sacc[nt][r] = p;
        ts += p;
      }
    ts += __shfl_xor(ts, 16);
    ts += __shfl_xor(ts, 32);
    l_run = l_run * alpha + ts;
    m_run = m_new;
#pragma unroll
    for (int mt = 0; mt < 16; mt++)
#pragma unroll
      for (int r = 0; r < 4; r++) Oacc[mt][r] *= alpha;
    // PV: O^T += Vt_frag * P_frag
#pragma unroll
    for (int s = 0; s < 2; s++) {
      bf16x8 pb;
#pragma unroll
      for (int r = 0; r < 4; r++) {
        pb[r] = (bf16)Sacc[2 * s][r];
        pb[4 + r] = (bf16)Sacc[2 * s + 1][r];
      }
#pragma unroll
      for (int mt = 0; mt < 16; mt++) {
        int d = mt * 16 + lane15;
        int slot = (g * 2 + s) ^ (d & 7);
        bf16x8 vf = *(const bf16x8*)(Vlds + d * 64 + slot * 8);
        Oacc[mt] = __builtin_amdgcn_mfma_f32_16x16x32_bf16(vf, pb, Oacc[mt], 0, 0, 0);
      }
    }
  }
  // epilogue: Oacc[mt][reg] = O^T[d = mt*16+4g+reg][q = lane15]
  float inv = 1.f / l_run;
  float* orow = Out + (size_t)(row0 + lane15) * 256 + g * 4;
#pragma unroll
  for (int mt = 0; mt < 16; mt++) {
    float4 o4 = make_float4(Oacc[mt][0] * inv, Oacc[mt][1] * inv,
                            Oacc[mt][2] * inv, Oacc[mt][3] * inv);
    *(float4*)(orow + mt * 16) = o4;
  }
}

__global__ void k_gru(float* __restrict__ h, const float* __restrict__ gi,
                      const float* __restrict__ gh) {
  int i = blockIdx.x * 256 + threadIdx.x;
  int v = i >> 8, d = i & 255;
  float gir = gi[v * 768 + d], giz = gi[v * 768 + 256 + d], gin = gi[v * 768 + 512 + d];
  float ghr = gh[v * 768 + d], ghz = gh[v * 768 + 256 + d], ghn = gh[v * 768 + 512 + d];
  float r = 1.f / (1.f + __expf(-(gir + ghr)));
  float z = 1.f / (1.f + __expf(-(giz + ghz)));
  float n = tanhf(gin + r * ghn);
  h[i] = (1.f - z) * n + z * h[i];
}

__global__ void k_gate(const float* __restrict__ h, const float* __restrict__ Wg,
                       const float* __restrict__ bg, float* __restrict__ g) {
  int wave = threadIdx.x >> 6, lane = threadIdx.x & 63;
  int v = blockIdx.x * 4 + wave;
  float s = 0.f;
#pragma unroll
  for (int k = lane; k < 256; k += 64) s += h[v * 256 + k] * Wg[k];
#pragma unroll
  for (int sh = 32; sh > 0; sh >>= 1) s += __shfl_xor(s, sh);
  if (lane == 0) g[v] = 1.f / (1.f + __expf(-(s + bg[0])));
}

__global__ void k_poolstats(const float* __restrict__ g, float* __restrict__ stats, int N) {
  __shared__ float red[256];
  int tid = threadIdx.x;
  float mx = -1e30f;
  for (int i = tid; i < N; i += 256) mx = fmaxf(mx, g[i]);
  red[tid] = mx;
  __syncthreads();
  for (int s = 128; s > 0; s >>= 1) {
    if (tid < s) red[tid] = fmaxf(red[tid], red[tid + s]);
    __syncthreads();
  }
  float M = red[0];
  __syncthreads();
  float sm = 0.f;
  for (int i = tid; i < N; i += 256) sm += __expf(g[i] - M);
  red[tid] = sm;
  __syncthreads();
  for (int s = 128; s > 0; s >>= 1) {
    if (tid < s) red[tid] += red[tid + s];
    __syncthreads();
  }
  if (tid == 0) { stats[0] = M; stats[1] = red[0]; }
}

__global__ void k_poolpart(const float* __restrict__ g, const float* __restrict__ h,
                           const float* __restrict__ stats, float* __restrict__ part, int N) {
  int c = blockIdx.x, o = threadIdx.x;
  int per = N / 32;
  float M = stats[0];
  float s = 0.f;
  for (int v = c * per; v < (c + 1) * per; v++) s += __expf(g[v] - M) * h[v * 256 + o];
  part[c * 256 + o] = s;
}

__global__ void k_poolfin(const float* __restrict__ part, const float* __restrict__ stats,
                          float* __restrict__ out) {
  int o = threadIdx.x;
  float s = 0.f;
#pragma unroll
  for (int c = 0; c < 32; c++) s += part[c * 256 + o];
  out[o] = s / stats[1];
}

extern "C" void kernel_launch(void* const* d_in, const int* in_sizes, int n_in,
                              void* d_out, int out_size, void* d_ws, size_t ws_size,
                              hipStream_t stream) {
  const int* x1 = (const int*)d_in[0];
  const int* x2 = (const int*)d_in[1];
  const int* ei1 = (const int*)d_in[2];
  const int* ei2 = (const int*)d_in[3];
  const int* ea1 = (const int*)d_in[4];
  const int* ea2 = (const int*)d_in[5];
  const float* embed = (const float*)d_in[6];
  const float* eemb = (const float*)d_in[7];
  const float* Wm = (const float*)d_in[8];
  const float* bm = (const float*)d_in[9];
  const float* Wih = (const float*)d_in[10];
  const float* Whh = (const float*)d_in[11];
  const float* bih = (const float*)d_in[12];
  const float* bhh = (const float*)d_in[13];
  const float* Wg = (const float*)d_in[14];
  const float* bg = (const float*)d_in[15];
  const int N = in_sizes[0];   // 8192
  const int E = in_sizes[4];   // 131072
  float* out = (float*)d_out;

  char* ws = (char*)d_ws;
  size_t ofs = 0;
  auto alloc = [&](size_t bytes) -> void* {
    void* p = ws + ofs;
    ofs = (ofs + bytes + 255) & ~(size_t)255;
    return p;
  };
  size_t ND4 = (size_t)N * 256 * 4;
  size_t ND2 = (size_t)N * 256 * 2;
  float* h1 = (float*)alloc(ND4);
  float* h2 = (float*)alloc(ND4);
  float* agg = (float*)alloc(ND4);
  float* M1 = (float*)alloc(ND4);
  float* M2 = (float*)alloc(ND4);
  float* at1 = (float*)alloc(ND4);
  float* at2 = (float*)alloc(ND4);
  float* C1 = (float*)alloc(ND4);
  float* C2 = (float*)alloc(ND4);
  float* gi = (float*)alloc((size_t)N * 768 * 4);
  float* gh = (float*)alloc((size_t)N * 768 * 4);
  bf16* hb1 = (bf16*)alloc(ND2);
  bf16* hb2 = (bf16*)alloc(ND2);
  bf16* hbt1 = (bf16*)alloc(ND2);
  bf16* hbt2 = (bf16*)alloc(ND2);
  float* P = (float*)alloc(16 * 256 * 4);
  unsigned* cnt1 = (unsigned*)alloc((size_t)N * 16 * 4);
  unsigned* cnt2 = (unsigned*)alloc((size_t)N * 16 * 4);
  unsigned* deg1 = (unsigned*)alloc((size_t)N * 4);
  unsigned* deg2 = (unsigned*)alloc((size_t)N * 4);
  unsigned* off1 = (unsigned*)alloc((size_t)(N + 1) * 4);
  unsigned* off2 = (unsigned*)alloc((size_t)(N + 1) * 4);
  unsigned* cur1 = (unsigned*)alloc((size_t)N * 4);
  unsigned* cur2 = (unsigned*)alloc((size_t)N * 4);
  int* csr1 = (int*)alloc((size_t)E * 4);
  int* csr2 = (int*)alloc((size_t)E * 4);
  float* gbuf = (float*)alloc((size_t)N * 4);
  float* partb = (float*)alloc(32 * 256 * 4);
  float* stats = (float*)alloc(256);

  size_t zbytes = (size_t)((char*)(deg2 + N) - (char*)cnt1);
  hipMemsetAsync(cnt1, 0, zbytes, stream);

  k_gather<<<N, 256, 0, stream>>>(embed, x1, h1);
  k_gather<<<N, 256, 0, stream>>>(embed, x2, h2);
  k_edgeproj<<<16, 256, 0, stream>>>(eemb, Wm, P);
  int eb = (E + 255) / 256;
  k_count<<<eb, 256, 0, stream>>>(ei1, ea1, cnt1, deg1, E);
  k_count<<<eb, 256, 0, stream>>>(ei2, ea2, cnt2, deg2, E);
  k_scan<<<1, 256, 0, stream>>>(deg1, off1, cur1, N);
  k_scan<<<1, 256, 0, stream>>>(deg2, off2, cur2, N);
  k_fill<<<eb, 256, 0, stream>>>(ei1, cur1, csr1, E);
  k_fill<<<eb, 256, 0, stream>>>(ei2, cur2, csr2, E);
  k_cconst<<<N, 256, 0, stream>>>(cnt1, deg1, P, bm, C1);
  k_cconst<<<N, 256, 0, stream>>>(cnt2, deg2, P, bm, C2);

  dim3 gM(N / 64, 4), gG(N / 64, 12), gC(N / 64, 4);
  for (int layer = 0; layer < 3; layer++) {
    k_aggh<<<N, 256, 0, stream>>>(h1, csr1, off1, agg);
    k_gemm<0><<<gM, 256, 0, stream>>>(h1, agg, nullptr, deg1, Wm, nullptr, C1, M1, 256, 768, 512);
    k_aggh<<<N, 256, 0, stream>>>(h2, csr2, off2, agg);
    k_gemm<0><<<gM, 256, 0, stream>>>(h2, agg, nullptr, deg2, Wm, nullptr, C2, M2, 256, 768, 512);
    k_cvt<<<gC, 1024, 0, stream>>>(h1, hb1, hbt1, N);
    k_cvt<<<gC, 1024, 0, stream>>>(h2, hb2, hbt2, N);
    k_flash_mfma<<<dim3(N / 64, 2), 256, 0, stream>>>(hb1, hbt1, hb2, hbt2, at1, at2, N);
    k_gemm<2><<<gG, 256, 0, stream>>>(h1, nullptr, nullptr, nullptr, Whh, bhh, nullptr, gh, 768, 256, 256);
    k_gemm<1><<<gG, 256, 0, stream>>>(M1, h1, at1, nullptr, Wih, bih, nullptr, gi, 768, 512, 512);
    k_gru<<<N, 256, 0, stream>>>(h1, gi, gh);
    k_gemm<2><<<gG, 256, 0, stream>>>(h2, nullptr, nullptr, nullptr, Whh, bhh, nullptr, gh, 768, 256, 256);
    k_gemm<1><<<gG, 256, 0, stream>>>(M2, h2, at2, nullptr, Wih, bih, nullptr, gi, 768, 512, 512);
    k_gru<<<N, 256, 0, stream>>>(h2, gi, gh);
  }

  k_gate<<<N / 4, 256, 0, stream>>>(h1, Wg, bg, gbuf);
  k_poolstats<<<1, 256, 0, stream>>>(gbuf, stats, N);
  k_poolpart<<<32, 256, 0, stream>>>(gbuf, h1, stats, partb, N);
  k_poolfin<<<1, 256, 0, stream>>>(partb, stats, out);
  k_gate<<<N / 4, 256, 0, stream>>>(h2, Wg, bg, gbuf);
  k_poolstats<<<1, 256, 0, stream>>>(gbuf, stats, N);
  k_poolpart<<<32, 256, 0, stream>>>(gbuf, h2, stats, partb, N);
  k_poolfin<<<1, 256, 0, stream>>>(partb, stats, out + 256);
}

// Round 3
// 1466.814 us; speedup vs baseline: 7.0220x; 1.9417x over previous
//
#include <hip/hip_runtime.h>

typedef __bf16 bf16;
typedef __attribute__((ext_vector_type(8))) __bf16 bf16x8;
typedef __attribute__((ext_vector_type(4))) float f32x4;
typedef unsigned int u32;

// ---------------------------------------------------------------------------
// GraphMatchNet: 3x { decomposed message GEMM (bf16 MFMA), dual MFMA flash
// attn (split-K x2), GRU (bf16 MFMA gate GEMMs) }
// ---------------------------------------------------------------------------

__global__ void k_gather(const float* __restrict__ emb, const int* __restrict__ x,
                         float* __restrict__ h) {
  int v = blockIdx.x, d = threadIdx.x;
  h[v * 256 + d] = emb[(size_t)x[v] * 256 + d];
}

__global__ void k_edgeproj(const float* __restrict__ ee, const float* __restrict__ Wm,
                           float* __restrict__ P) {
  __shared__ float row[256];
  int a = blockIdx.x, o = threadIdx.x;
  row[o] = ee[a * 256 + o];
  __syncthreads();
  float s = 0.f;
#pragma unroll 8
  for (int k = 0; k < 256; k++) s += row[k] * Wm[o * 768 + 512 + k];
  P[a * 256 + o] = s;
}

__global__ void k_count(const int* __restrict__ ei, const int* __restrict__ ea,
                        unsigned* __restrict__ cnt, unsigned* __restrict__ deg, int E) {
  int e = blockIdx.x * 256 + threadIdx.x;
  if (e >= E) return;
  int dst = ei[E + e];
  atomicAdd(&cnt[dst * 16 + ea[e]], 1u);
  atomicAdd(&deg[dst], 1u);
}

__global__ void k_scan(const unsigned* __restrict__ deg, unsigned* __restrict__ off,
                       unsigned* __restrict__ cur, int N) {
  __shared__ unsigned part[256];
  int tid = threadIdx.x;
  int per = N >> 8;
  unsigned s = 0;
  for (int i = 0; i < per; i++) s += deg[tid * per + i];
  part[tid] = s;
  __syncthreads();
  if (tid == 0) {
    unsigned run = 0;
    for (int i = 0; i < 256; i++) { unsigned t = part[i]; part[i] = run; run += t; }
  }
  __syncthreads();
  unsigned run = part[tid];
  for (int i = 0; i < per; i++) {
    unsigned dv = deg[tid * per + i];
    off[tid * per + i] = run;
    cur[tid * per + i] = run;
    run += dv;
  }
  if (tid == 255) off[N] = run;
}

__global__ void k_fill(const int* __restrict__ ei, unsigned* __restrict__ cur,
                       int* __restrict__ csr, int E) {
  int e = blockIdx.x * 256 + threadIdx.x;
  if (e >= E) return;
  int dst = ei[E + e];
  unsigned pos = atomicAdd(&cur[dst], 1u);
  csr[pos] = ei[e];  // src
}

__global__ void k_cconst(const unsigned* __restrict__ cnt, const unsigned* __restrict__ deg,
                         const float* __restrict__ P, const float* __restrict__ bm,
                         float* __restrict__ C) {
  int v = blockIdx.x, o = threadIdx.x;
  float s = (float)deg[v] * bm[o];
#pragma unroll
  for (int a = 0; a < 16; a++) s += (float)cnt[v * 16 + a] * P[a * 256 + o];
  C[v * 256 + o] = s;
}

// pack f32 weight [O][srcStride] -> bf16 [O][K]
__global__ void k_packw(const float* __restrict__ src, bf16* __restrict__ dst,
                        int srcStride, int K) {
  int o = blockIdx.x;
  for (int k = threadIdx.x; k < K; k += 256)
    dst[(size_t)o * K + k] = (bf16)src[(size_t)o * srcStride + k];
}

// A0b[v] = [ bf16(deg*h[v]) | bf16(sum_{src in N(v)} h[src]) ]
__global__ void k_aggA0(const float* __restrict__ h, const int* __restrict__ csr,
                        const unsigned* __restrict__ off, bf16* __restrict__ A0b) {
  int v = blockIdx.x, d = threadIdx.x;
  unsigned i0 = off[v], i1 = off[v + 1];
  float s = 0.f;
  for (unsigned i = i0; i < i1; i++) s += h[csr[i] * 256 + d];
  A0b[(size_t)v * 512 + 256 + d] = (bf16)s;
  A0b[(size_t)v * 512 + d] = (bf16)(h[v * 256 + d] * (float)(i1 - i0));
}

// convert h (f32 [N][256]) -> hb (bf16 [N][256]) and hbt (bf16 [256][N])
__global__ void k_cvt(const float* __restrict__ h, bf16* __restrict__ hb,
                      bf16* __restrict__ hbt, int N) {
  __shared__ bf16 t[64][68];
  int v0 = blockIdx.x * 64, d0 = blockIdx.y * 64;
  int tid = threadIdx.x;
#pragma unroll
  for (int i = 0; i < 4; i++) {
    int e = tid + i * 1024;
    int r = e >> 6, c = e & 63;
    bf16 b = (bf16)h[(size_t)(v0 + r) * 256 + d0 + c];
    hb[(size_t)(v0 + r) * 256 + d0 + c] = b;
    t[r][c] = b;
  }
  __syncthreads();
#pragma unroll
  for (int i = 0; i < 4; i++) {
    int e = tid + i * 1024;
    int dr = e >> 6, vc = e & 63;
    hbt[(size_t)(d0 + dr) * N + v0 + vc] = t[vc][dr];
  }
}

__device__ __forceinline__ void gl2lds16(const bf16* g, bf16* l) {
  __builtin_amdgcn_global_load_lds(
      (const __attribute__((address_space(1))) u32*)(const void*)g,
      (__attribute__((address_space(3))) u32*)(void*)l, 16, 0, 0);
}

// ---------------------------------------------------------------------------
// bf16 MFMA GEMM: out[row][col] = sum_k A[row][k] * W[col][k] (+ epilogue).
// A bf16 [M][sA] row-major, W bf16 [Ncols][K] packed row-major.
// 128x128 tile, BK=64, 4 waves, dbuf LDS, global_load_lds w/ XOR-swizzled
// source (col8 ^= row&7) and matching swizzled ds_read (rule both-sides).
// MODE 0: += Cmat (f32 [M][256]), out bf16 stride 512 (GI A-matrix cols 0..255)
// MODE 1: += bias (f32 [Ncols]), out f32 stride sOut
// ---------------------------------------------------------------------------
template <int MODE>
__global__ __launch_bounds__(256, 2) void k_gemm_mfma(
    const bf16* __restrict__ A, int sA, const bf16* __restrict__ W,
    const float* __restrict__ biasC, float* __restrict__ outf,
    bf16* __restrict__ outb, int sOut, int K) {
  __shared__ bf16 lds[2][2][128 * 64];
  int tid = threadIdx.x;
  int w = tid >> 6, l = tid & 63;
  int lane15 = l & 15, g = l >> 4;
  int wr = w >> 1, wc = w & 1;
  int row0 = blockIdx.x * 128, col0 = blockIdx.y * 128;

  const bf16* Abase = A + (size_t)row0 * sA;
  const bf16* Wbase = W + (size_t)col0 * K;

  auto stage = [&](int buf, int kt) {
#pragma unroll
    for (int i = 0; i < 4; i++) {
      int c = w * 256 + i * 64 + l;       // chunk 0..1023
      int r = c >> 3, c8 = c & 7;
      int sc8 = c8 ^ (r & 7);             // pre-swizzled source column
      gl2lds16(Abase + (size_t)r * sA + kt + sc8 * 8,
               &lds[buf][0][(w * 256 + i * 64) * 8]);
      gl2lds16(Wbase + (size_t)r * K + kt + sc8 * 8,
               &lds[buf][1][(w * 256 + i * 64) * 8]);
    }
  };

  f32x4 acc[4][4];
#pragma unroll
  for (int a = 0; a < 4; a++)
#pragma unroll
    for (int b = 0; b < 4; b++) acc[a][b] = (f32x4){0.f, 0.f, 0.f, 0.f};

  stage(0, 0);
  __syncthreads();
  int nk = K >> 6;
  for (int t = 0; t < nk; t++) {
    int buf = t & 1;
    if (t + 1 < nk) stage(buf ^ 1, (t + 1) << 6);
    const bf16* La = lds[buf][0];
    const bf16* Lb = lds[buf][1];
    bf16x8 af[4][2], bfr[4][2];
#pragma unroll
    for (int mt = 0; mt < 4; mt++) {
      int r = wr * 64 + mt * 16 + lane15;
#pragma unroll
      for (int kk = 0; kk < 2; kk++)
        af[mt][kk] = *(const bf16x8*)(La + r * 64 + (((kk * 4 + g) ^ (r & 7)) * 8));
    }
#pragma unroll
    for (int nt = 0; nt < 4; nt++) {
      int cl = wc * 64 + nt * 16 + lane15;
#pragma unroll
      for (int kk = 0; kk < 2; kk++)
        bfr[nt][kk] = *(const bf16x8*)(Lb + cl * 64 + (((kk * 4 + g) ^ (cl & 7)) * 8));
    }
#pragma unroll
    for (int kk = 0; kk < 2; kk++)
#pragma unroll
      for (int mt = 0; mt < 4; mt++)
#pragma unroll
        for (int nt = 0; nt < 4; nt++)
          acc[mt][nt] =
              __builtin_amdgcn_mfma_f32_16x16x32_bf16(af[mt][kk], bfr[nt][kk], acc[mt][nt], 0, 0, 0);
    __syncthreads();  // drains vmcnt (stage) + lgkm; safe to flip buffers
  }
#pragma unroll
  for (int mt = 0; mt < 4; mt++)
#pragma unroll
    for (int nt = 0; nt < 4; nt++) {
      int col = col0 + wc * 64 + nt * 16 + lane15;
#pragma unroll
      for (int r = 0; r < 4; r++) {
        int row = row0 + wr * 64 + mt * 16 + g * 4 + r;
        float v = acc[mt][nt][r];
        if (MODE == 0)
          outb[(size_t)row * 512 + col] = (bf16)(v + biasC[(size_t)row * 256 + col]);
        else
          outf[(size_t)row * sOut + col] = v + biasC[col];
      }
    }
}

// ---------------------------------------------------------------------------
// MFMA flash attention, split-K x2. blockIdx.y: bit0 = direction, bit1 = half.
// Writes unnormalized O + (m,l) stats; k_comb merges halves and emits
// bf16(h - att) into the GI A-matrix cols 256..511.
// ---------------------------------------------------------------------------
__global__ __launch_bounds__(256, 2) void k_flash_mfma(
    const bf16* __restrict__ hb1, const bf16* __restrict__ hbt1,
    const bf16* __restrict__ hb2, const bf16* __restrict__ hbt2,
    float* __restrict__ Opart, float2* __restrict__ ml, int N) {
  int dir = blockIdx.y & 1, half = blockIdx.y >> 1;
  const bf16 *Q, *K, *Kt;
  if (dir == 0) { Q = hb1; K = hb2; Kt = hbt2; }
  else          { Q = hb2; K = hb1; Kt = hbt1; }
  int idx = dir * 2 + half;
  float* Out = Opart + (size_t)idx * N * 256;
  float2* mlp = ml + (size_t)idx * N;

  __shared__ bf16 Klds[64 * 256];
  __shared__ bf16 Vlds[256 * 64];
  int tid = threadIdx.x;
  int w = tid >> 6, l = tid & 63;
  int lane15 = l & 15, g = l >> 4;
  int row0 = blockIdx.x * 64 + w * 16;

  bf16x8 qf[8];
  {
    const bf16* qp = Q + (size_t)(row0 + lane15) * 256 + g * 8;
#pragma unroll
    for (int kk = 0; kk < 8; kk++) qf[kk] = *(const bf16x8*)(qp + kk * 32);
  }
  f32x4 Oacc[16];
#pragma unroll
  for (int i = 0; i < 16; i++) Oacc[i] = (f32x4){0.f, 0.f, 0.f, 0.f};
  float m_run = -1e30f, l_run = 0.f;

  int halfN = N >> 1;
  int kt0 = half * halfN;
  for (int kt = kt0; kt < kt0 + halfN; kt += 64) {
    __syncthreads();
#pragma unroll
    for (int i = 0; i < 8; i++) {
      int c = tid + i * 256;
      int key = c >> 5, sl = c & 31;
      float4 v = *(const float4*)(const void*)(K + (size_t)(kt + key) * 256 + sl * 8);
      *(float4*)(void*)(Klds + key * 256 + ((sl ^ (key & 7)) * 8)) = v;
    }
#pragma unroll
    for (int i = 0; i < 16; i++) {
      int c = tid + i * 256;
      int d = c >> 4, j = c & 15;
      float2 v = *(const float2*)(const void*)(Kt + (size_t)d * N + kt + (j & 3) * 16 + (j >> 2) * 4);
      int slot = (j >> 1) ^ (d & 7);
      *(float2*)(void*)(Vlds + d * 64 + slot * 8 + (j & 1) * 4) = v;
    }
    __syncthreads();

    f32x4 Sacc[4];
#pragma unroll
    for (int i = 0; i < 4; i++) Sacc[i] = (f32x4){0.f, 0.f, 0.f, 0.f};
#pragma unroll
    for (int kk = 0; kk < 8; kk++) {
#pragma unroll
      for (int nt = 0; nt < 4; nt++) {
        int key = nt * 16 + lane15;
        int slot = (kk * 4 + g) ^ (key & 7);
        bf16x8 kf = *(const bf16x8*)(Klds + key * 256 + slot * 8);
        Sacc[nt] = __builtin_amdgcn_mfma_f32_16x16x32_bf16(kf, qf[kk], Sacc[nt], 0, 0, 0);
      }
    }
    float tmax = -1e30f;
#pragma unroll
    for (int nt = 0; nt < 4; nt++)
#pragma unroll
      for (int r = 0; r < 4; r++) tmax = fmaxf(tmax, Sacc[nt][r]);
    tmax = fmaxf(tmax, __shfl_xor(tmax, 16));
    tmax = fmaxf(tmax, __shfl_xor(tmax, 32));
    float m_new = fmaxf(m_run, tmax);
    float alpha = __expf(m_run - m_new);
    float ts = 0.f;
#pragma unroll
    for (int nt = 0; nt < 4; nt++)
#pragma unroll
      for (int r = 0; r < 4; r++) {
        float p = __expf(Sacc[nt][r] - m_new);
        Sacc[nt][r] = p;
        ts += p;
      }
    ts += __shfl_xor(ts, 16);
    ts += __shfl_xor(ts, 32);
    l_run = l_run * alpha + ts;
    m_run = m_new;
#pragma unroll
    for (int mt = 0; mt < 16; mt++)
#pragma unroll
      for (int r = 0; r < 4; r++) Oacc[mt][r] *= alpha;
#pragma unroll
    for (int s = 0; s < 2; s++) {
      bf16x8 pb;
#pragma unroll
      for (int r = 0; r < 4; r++) {
        pb[r] = (bf16)Sacc[2 * s][r];
        pb[4 + r] = (bf16)Sacc[2 * s + 1][r];
      }
#pragma unroll
      for (int mt = 0; mt < 16; mt++) {
        int d = mt * 16 + lane15;
        int slot = (g * 2 + s) ^ (d & 7);
        bf16x8 vf = *(const bf16x8*)(Vlds + d * 64 + slot * 8);
        Oacc[mt] = __builtin_amdgcn_mfma_f32_16x16x32_bf16(vf, pb, Oacc[mt], 0, 0, 0);
      }
    }
  }
  float* orow = Out + (size_t)(row0 + lane15) * 256 + g * 4;
#pragma unroll
  for (int mt = 0; mt < 16; mt++) {
    f32x4 o = Oacc[mt];
    *(float4*)(orow + mt * 16) = make_float4(o[0], o[1], o[2], o[3]);
  }
  if (g == 0) mlp[row0 + lane15] = make_float2(m_run, l_run);
}

// merge the two key-halves; A1b[row][256+d] = bf16(h[row][d] - att[row][d])
__global__ void k_comb(const float* __restrict__ O0, const float* __restrict__ O1,
                       const float2* __restrict__ ml0, const float2* __restrict__ ml1,
                       const bf16* __restrict__ hb, bf16* __restrict__ A1b) {
  int row = blockIdx.x, d = threadIdx.x;
  float2 s0 = ml0[row], s1 = ml1[row];
  float m = fmaxf(s0.x, s1.x);
  float a0 = __expf(s0.x - m), a1 = __expf(s1.x - m);
  float denom = s0.y * a0 + s1.y * a1;
  float o = (O0[(size_t)row * 256 + d] * a0 + O1[(size_t)row * 256 + d] * a1) / denom;
  float hv = (float)hb[(size_t)row * 256 + d];
  A1b[(size_t)row * 512 + 256 + d] = (bf16)(hv - o);
}

__global__ void k_gru(float* __restrict__ h, const float* __restrict__ gi,
                      const float* __restrict__ gh) {
  int i = blockIdx.x * 256 + threadIdx.x;
  int v = i >> 8, d = i & 255;
  float gir = gi[v * 768 + d], giz = gi[v * 768 + 256 + d], gin = gi[v * 768 + 512 + d];
  float ghr = gh[v * 768 + d], ghz = gh[v * 768 + 256 + d], ghn = gh[v * 768 + 512 + d];
  float r = 1.f / (1.f + __expf(-(gir + ghr)));
  float z = 1.f / (1.f + __expf(-(giz + ghz)));
  float n = tanhf(gin + r * ghn);
  h[i] = (1.f - z) * n + z * h[i];
}

__global__ void k_gate(const float* __restrict__ h, const float* __restrict__ Wg,
                       const float* __restrict__ bg, float* __restrict__ g) {
  int wave = threadIdx.x >> 6, lane = threadIdx.x & 63;
  int v = blockIdx.x * 4 + wave;
  float s = 0.f;
#pragma unroll
  for (int k = lane; k < 256; k += 64) s += h[v * 256 + k] * Wg[k];
#pragma unroll
  for (int sh = 32; sh > 0; sh >>= 1) s += __shfl_xor(s, sh);
  if (lane == 0) g[v] = 1.f / (1.f + __expf(-(s + bg[0])));
}

__global__ void k_poolstats(const float* __restrict__ g, float* __restrict__ stats, int N) {
  __shared__ float red[256];
  int tid = threadIdx.x;
  float mx = -1e30f;
  for (int i = tid; i < N; i += 256) mx = fmaxf(mx, g[i]);
  red[tid] = mx;
  __syncthreads();
  for (int s = 128; s > 0; s >>= 1) {
    if (tid < s) red[tid] = fmaxf(red[tid], red[tid + s]);
    __syncthreads();
  }
  float M = red[0];
  __syncthreads();
  float sm = 0.f;
  for (int i = tid; i < N; i += 256) sm += __expf(g[i] - M);
  red[tid] = sm;
  __syncthreads();
  for (int s = 128; s > 0; s >>= 1) {
    if (tid < s) red[tid] += red[tid + s];
    __syncthreads();
  }
  if (tid == 0) { stats[0] = M; stats[1] = red[0]; }
}

__global__ void k_poolpart(const float* __restrict__ g, const float* __restrict__ h,
                           const float* __restrict__ stats, float* __restrict__ part, int N) {
  int c = blockIdx.x, o = threadIdx.x;
  int per = N / 32;
  float M = stats[0];
  float s = 0.f;
  for (int v = c * per; v < (c + 1) * per; v++) s += __expf(g[v] - M) * h[v * 256 + o];
  part[c * 256 + o] = s;
}

__global__ void k_poolfin(const float* __restrict__ part, const float* __restrict__ stats,
                          float* __restrict__ out) {
  int o = threadIdx.x;
  float s = 0.f;
#pragma unroll
  for (int c = 0; c < 32; c++) s += part[c * 256 + o];
  out[o] = s / stats[1];
}

extern "C" void kernel_launch(void* const* d_in, const int* in_sizes, int n_in,
                              void* d_out, int out_size, void* d_ws, size_t ws_size,
                              hipStream_t stream) {
  const int* x1 = (const int*)d_in[0];
  const int* x2 = (const int*)d_in[1];
  const int* ei1 = (const int*)d_in[2];
  const int* ei2 = (const int*)d_in[3];
  const int* ea1 = (const int*)d_in[4];
  const int* ea2 = (const int*)d_in[5];
  const float* embed = (const float*)d_in[6];
  const float* eemb = (const float*)d_in[7];
  const float* Wm = (const float*)d_in[8];
  const float* bm = (const float*)d_in[9];
  const float* Wih = (const float*)d_in[10];
  const float* Whh = (const float*)d_in[11];
  const float* bih = (const float*)d_in[12];
  const float* bhh = (const float*)d_in[13];
  const float* Wg = (const float*)d_in[14];
  const float* bg = (const float*)d_in[15];
  const int N = in_sizes[0];   // 8192
  const int E = in_sizes[4];   // 131072
  float* out = (float*)d_out;

  char* ws = (char*)d_ws;
  size_t ofs = 0;
  auto alloc = [&](size_t bytes) -> void* {
    void* p = ws + ofs;
    ofs = (ofs + bytes + 255) & ~(size_t)255;
    return p;
  };
  size_t ND4 = (size_t)N * 256 * 4;
  size_t ND2 = (size_t)N * 256 * 2;
  size_t NP = (size_t)N * 256;  // floats per (dir,half) O-partial
  float* h1 = (float*)alloc(ND4);
  float* h2 = (float*)alloc(ND4);
  float* C1 = (float*)alloc(ND4);
  float* C2 = (float*)alloc(ND4);
  // big region: gi|gh (each N*768 f32); Opart (4*N*256 f32) aliases it
  float* big = (float*)alloc((size_t)N * 768 * 4 * 2);
  float* gi = big;
  float* gh = big + (size_t)N * 768;
  float* Opart = big;
  bf16* hb1 = (bf16*)alloc(ND2);
  bf16* hb2 = (bf16*)alloc(ND2);
  bf16* hbt1 = (bf16*)alloc(ND2);
  bf16* hbt2 = (bf16*)alloc(ND2);
  bf16* A0b = (bf16*)alloc((size_t)N * 512 * 2);
  bf16* A1b1 = (bf16*)alloc((size_t)N * 512 * 2);
  bf16* A1b2 = (bf16*)alloc((size_t)N * 512 * 2);
  bf16* Wmb = (bf16*)alloc((size_t)256 * 512 * 2);
  bf16* Wihb = (bf16*)alloc((size_t)768 * 512 * 2);
  bf16* Whhb = (bf16*)alloc((size_t)768 * 256 * 2);
  float2* ml = (float2*)alloc((size_t)4 * N * 8);
  float* P = (float*)alloc(16 * 256 * 4);
  unsigned* cnt1 = (unsigned*)alloc((size_t)N * 16 * 4);
  unsigned* cnt2 = (unsigned*)alloc((size_t)N * 16 * 4);
  unsigned* deg1 = (unsigned*)alloc((size_t)N * 4);
  unsigned* deg2 = (unsigned*)alloc((size_t)N * 4);
  unsigned* off1 = (unsigned*)alloc((size_t)(N + 1) * 4);
  unsigned* off2 = (unsigned*)alloc((size_t)(N + 1) * 4);
  unsigned* cur1 = (unsigned*)alloc((size_t)N * 4);
  unsigned* cur2 = (unsigned*)alloc((size_t)N * 4);
  int* csr1 = (int*)alloc((size_t)E * 4);
  int* csr2 = (int*)alloc((size_t)E * 4);
  float* gbuf = (float*)alloc((size_t)N * 4);
  float* partb = (float*)alloc(32 * 256 * 4);
  float* stats = (float*)alloc(256);

  size_t zbytes = (size_t)((char*)(deg2 + N) - (char*)cnt1);
  hipMemsetAsync(cnt1, 0, zbytes, stream);

  k_gather<<<N, 256, 0, stream>>>(embed, x1, h1);
  k_gather<<<N, 256, 0, stream>>>(embed, x2, h2);
  k_edgeproj<<<16, 256, 0, stream>>>(eemb, Wm, P);
  k_packw<<<256, 256, 0, stream>>>(Wm, Wmb, 768, 512);
  k_packw<<<768, 256, 0, stream>>>(Wih, Wihb, 512, 512);
  k_packw<<<768, 256, 0, stream>>>(Whh, Whhb, 256, 256);
  int eb = (E + 255) / 256;
  k_count<<<eb, 256, 0, stream>>>(ei1, ea1, cnt1, deg1, E);
  k_count<<<eb, 256, 0, stream>>>(ei2, ea2, cnt2, deg2, E);
  k_scan<<<1, 256, 0, stream>>>(deg1, off1, cur1, N);
  k_scan<<<1, 256, 0, stream>>>(deg2, off2, cur2, N);
  k_fill<<<eb, 256, 0, stream>>>(ei1, cur1, csr1, E);
  k_fill<<<eb, 256, 0, stream>>>(ei2, cur2, csr2, E);
  k_cconst<<<N, 256, 0, stream>>>(cnt1, deg1, P, bm, C1);
  k_cconst<<<N, 256, 0, stream>>>(cnt2, deg2, P, bm, C2);

  dim3 gC(N / 64, 4);
  for (int layer = 0; layer < 3; layer++) {
    // messages -> bf16 M written into GI A-matrix cols 0..255
    k_aggA0<<<N, 256, 0, stream>>>(h1, csr1, off1, A0b);
    k_gemm_mfma<0><<<dim3(N / 128, 2), 256, 0, stream>>>(A0b, 512, Wmb, C1, nullptr, A1b1, 0, 512);
    k_aggA0<<<N, 256, 0, stream>>>(h2, csr2, off2, A0b);
    k_gemm_mfma<0><<<dim3(N / 128, 2), 256, 0, stream>>>(A0b, 512, Wmb, C2, nullptr, A1b2, 0, 512);
    // bf16 snapshots for flash + gate GEMMs
    k_cvt<<<gC, 1024, 0, stream>>>(h1, hb1, hbt1, N);
    k_cvt<<<gC, 1024, 0, stream>>>(h2, hb2, hbt2, N);
    // cross-attention (both dirs, split-K x2) + merge into GI A cols 256..511
    k_flash_mfma<<<dim3(N / 64, 4), 256, 0, stream>>>(hb1, hbt1, hb2, hbt2, Opart, ml, N);
    k_comb<<<N, 256, 0, stream>>>(Opart, Opart + NP, ml, ml + N, hb1, A1b1);
    k_comb<<<N, 256, 0, stream>>>(Opart + 2 * NP, Opart + 3 * NP, ml + 2 * N, ml + 3 * N, hb2, A1b2);
    // graph 1 GRU
    k_gemm_mfma<1><<<dim3(N / 128, 6), 256, 0, stream>>>(hb1, 256, Whhb, bhh, gh, nullptr, 768, 256);
    k_gemm_mfma<1><<<dim3(N / 128, 6), 256, 0, stream>>>(A1b1, 512, Wihb, bih, gi, nullptr, 768, 512);
    k_gru<<<N, 256, 0, stream>>>(h1, gi, gh);
    // graph 2 GRU
    k_gemm_mfma<1><<<dim3(N / 128, 6), 256, 0, stream>>>(hb2, 256, Whhb, bhh, gh, nullptr, 768, 256);
    k_gemm_mfma<1><<<dim3(N / 128, 6), 256, 0, stream>>>(A1b2, 512, Wihb, bih, gi, nullptr, 768, 512);
    k_gru<<<N, 256, 0, stream>>>(h2, gi, gh);
  }

  k_gate<<<N / 4, 256, 0, stream>>>(h1, Wg, bg, gbuf);
  k_poolstats<<<1, 256, 0, stream>>>(gbuf, stats, N);
  k_poolpart<<<32, 256, 0, stream>>>(gbuf, h1, stats, partb, N);
  k_poolfin<<<1, 256, 0, stream>>>(partb, stats, out);
  k_gate<<<N / 4, 256, 0, stream>>>(h2, Wg, bg, gbuf);
  k_poolstats<<<1, 256, 0, stream>>>(gbuf, stats, N);
  k_poolpart<<<32, 256, 0, stream>>>(gbuf, h2, stats, partb, N);
  k_poolfin<<<1, 256, 0, stream>>>(partb, stats, out + 256);
}